// Round 6
// baseline (198.697 us; speedup 1.0000x reference)
//
#include <hip/hip_runtime.h>
#include <math.h>

#define F 128
#define CAP 2688     // max edges per 64-dst bucket (mean 2048, sigma ~45 -> +14 sigma)
#define SCHUNK 3200  // per-block dst LDS staging capacity (E/512 = 3128 at E=1.6M)
#define SCANB 512    // scan-role blocks in k_main (2 scan blocks/CU -> 32 waves/CU)
typedef unsigned long long ull;
typedef unsigned int uint;
typedef float f32x4 __attribute__((ext_vector_type(4)));
typedef short bf16x8 __attribute__((ext_vector_type(8)));   // 8 bf16 = 4 VGPRs (guide §3)

// edge record in ebin: [w:32][dlow:6][src:20]  (src < 2^20, dlow = dst & 63)
// ebin layout: bucket b owns slots [b*CAP, (b+1)*CAP); cursor[b]-b*CAP = count
// hs4: fp4 e2m1 (global scale 2), 128 feats x 4 bits = 64 B/row -> 3.2 MB total
// WT : bf16 transpose of (W[0]+W[1]), [n][k] layout, 32 KB (L1/L2-resident)

// ---------- fp4 helpers ----------
__device__ __forceinline__ uint fp4_enc(float v) {
    uint s = (__float_as_uint(v) >> 28) & 8u;
    float af = fabsf(v);
    uint c = af < 0.5f ? 0u : af < 1.5f ? 1u : af < 2.5f ? 2u : af < 3.5f ? 3u
           : af < 5.0f ? 4u : af < 7.0f ? 5u : af < 10.0f ? 6u : 7u;
    return s | c;
}

#if __has_builtin(__builtin_amdgcn_cvt_scalef32_pk_f32_fp4)
__device__ __forceinline__ void dec8_fma(uint x, float w, float* acc) {
    auto p0 = __builtin_amdgcn_cvt_scalef32_pk_f32_fp4(x, 2.0f, 0);
    auto p1 = __builtin_amdgcn_cvt_scalef32_pk_f32_fp4(x, 2.0f, 1);
    auto p2 = __builtin_amdgcn_cvt_scalef32_pk_f32_fp4(x, 2.0f, 2);
    auto p3 = __builtin_amdgcn_cvt_scalef32_pk_f32_fp4(x, 2.0f, 3);
    acc[0] += w * p0[0]; acc[1] += w * p0[1];
    acc[2] += w * p1[0]; acc[3] += w * p1[1];
    acc[4] += w * p2[0]; acc[5] += w * p2[1];
    acc[6] += w * p3[0]; acc[7] += w * p3[1];
}
#else
__device__ __forceinline__ uint fp4x4_to_fp8x4(uint b) {
    uint mag = b & 0x07070707u;
    uint sgn = (b & 0x08080808u) << 4;
    uint g2  = ((mag >> 1) | (mag >> 2)) & 0x01010101u;
    uint msk = g2 * 0xFFu;
    uint A   = 0x30303030u + (mag << 2);
    uint B   = (mag & 0x01010101u) * 0x30u;
    return sgn | (msk & A) | (~msk & B);
}
__device__ __forceinline__ void dec8_fma(uint x, float w, float* acc) {
    uint lo = x & 0x0F0F0F0Fu;
    uint hi = (x >> 4) & 0x0F0F0F0Fu;
    uint f8l = fp4x4_to_fp8x4(lo);
    uint f8h = fp4x4_to_fp8x4(hi);
    auto p0 = __builtin_amdgcn_cvt_pk_f32_fp8(f8l, false);
    auto p1 = __builtin_amdgcn_cvt_pk_f32_fp8(f8l, true);
    auto p2 = __builtin_amdgcn_cvt_pk_f32_fp8(f8h, false);
    auto p3 = __builtin_amdgcn_cvt_pk_f32_fp8(f8h, true);
    float w2 = w * 2.0f;
    acc[0] += w2 * p0[0]; acc[2] += w2 * p0[1]; acc[4] += w2 * p1[0]; acc[6] += w2 * p1[1];
    acc[1] += w2 * p2[0]; acc[3] += w2 * p2[1]; acc[5] += w2 * p3[0]; acc[7] += w2 * p3[1];
}
#endif

// float -> bf16 (RNE), pack two into a uint
__device__ __forceinline__ uint pk_bf16(float a, float b) {
    uint ua = __float_as_uint(a); ua = (ua + 0x7FFFu + ((ua >> 16) & 1u)) >> 16;
    uint ub = __float_as_uint(b); ub = (ub + 0x7FFFu + ((ub >> 16) & 1u)) >> 16;
    return ua | (ub << 16);
}

// ---------- kernels ----------
// setup: WT[n][k] = bf16(W[0][k][n] + W[1][k][n]); cursor[i] = i*CAP; scal = 0
__global__ void k_setup(float* __restrict__ scal, int* __restrict__ bucketCursor,
                        const float* __restrict__ W, unsigned short* __restrict__ WT, int NBK) {
    int i = blockIdx.x * 256 + threadIdx.x;
    if (i < F * F) {
        int k = i >> 7, n = i & 127;
        float v = W[i] + W[F * F + i];
        uint u = __float_as_uint(v);
        u = (u + 0x7FFFu + ((u >> 16) & 1u)) >> 16;
        WT[n * F + k] = (unsigned short)u;
    }
    if (i < 16) scal[i] = 0.0f;
    if (i < NBK) bucketCursor[i] = i * CAP;
}

// k_main: heterogeneous roles in one dispatch.
//   blocks [0, SCANB):         edge scan -> packed ebin records + softmax denom
//   blocks [SCANB, SCANB+GB):  256-row bf16-MFMA tile of hs4 = fp4(h @ Wsum)
// 64 KB LDS -> 2 blocks/CU resident (32 waves/CU); 708 blocks, 512 resident slots.
// launch_bounds (1024,4): VGPR cap 64 = gemm role's natural usage (r2: 64, no spill).
__global__ __launch_bounds__(1024, 4) void k_main(const float* __restrict__ h,
                                                  const unsigned short* __restrict__ WT,
                                                  unsigned short* __restrict__ hs4, int N,
                                                  const int* __restrict__ src,
                                                  const int* __restrict__ dst,
                                                  const float* __restrict__ ef, int E, int NBK,
                                                  int* __restrict__ bucketCursor,
                                                  ull* __restrict__ ebin,
                                                  float* __restrict__ scal) {
    __shared__ __align__(16) char sm[65536];   // union: scan ~21KB | gemm 64KB (ldsA reused as ldsO)
    int t = threadIdx.x;

    if (blockIdx.x >= SCANB) {
        // ================= GEMM role: 256 rows/block, 16 waves =================
        char* ldsA = sm;   // 256 rows x 256 B (bf16, XOR-swizzled); reused for fp4 out after MFMA
        int row0 = (int)(blockIdx.x - SCANB) * 256;

        // stage h tile -> bf16 LDS; chunk = 16 B (8 feats); byte ^= (row&7)<<4 (G4 swizzle)
        for (int c = t; c < 256 * 16; c += 1024) {
            int r = c >> 4, cc = c & 15;
            float4 v0 = make_float4(0.f, 0.f, 0.f, 0.f), v1 = v0;
            if (row0 + r < N) {
                const float4* hp = (const float4*)(h + (size_t)(row0 + r) * F + cc * 8);
                v0 = hp[0]; v1 = hp[1];
            }
            uint4 b;
            b.x = pk_bf16(v0.x, v0.y); b.y = pk_bf16(v0.z, v0.w);
            b.z = pk_bf16(v1.x, v1.y); b.w = pk_bf16(v1.z, v1.w);
            *(uint4*)(ldsA + (r * 256 + ((cc * 16) ^ ((r & 7) << 4)))) = b;
        }
        __syncthreads();

        int lane = t & 63, wid = t >> 6;
        int lr = lane & 15;        // row within wave's 16-row slice / WT row within n-tile
        int kg = lane >> 4;        // k-group 0..3 (8 bf16 each)
        int lrow = wid * 16 + lr;  // LDS row 0..255

        f32x4 acc[8];
        #pragma unroll
        for (int ct = 0; ct < 8; ++ct) acc[ct] = (f32x4){0.f, 0.f, 0.f, 0.f};

        #pragma unroll
        for (int ks = 0; ks < 4; ++ks) {
            bf16x8 bh = *(const bf16x8*)(ldsA + (lrow * 256 + ((ks * 64 + kg * 16) ^ ((lrow & 7) << 4))));
            #pragma unroll
            for (int ct = 0; ct < 8; ++ct) {
                bf16x8 aw = *(const bf16x8*)(WT + (size_t)(16 * ct + lr) * F + ks * 32 + kg * 8);
                acc[ct] = __builtin_amdgcn_mfma_f32_16x16x32_bf16(aw, bh, acc[ct], 0, 0, 0);
            }
        }
        __syncthreads();   // all ds_reads of ldsA consumed into acc -> safe to reuse

        // pack fp4 nibbles into reused LDS: lane holds 4 consecutive cols per tile
        unsigned short* ldsO = (unsigned short*)sm;   // 256 rows x 64 B fp4 (16 KB)
        #pragma unroll
        for (int ct = 0; ct < 8; ++ct) {
            uint c = fp4_enc(acc[ct][0]) | (fp4_enc(acc[ct][1]) << 4)
                   | (fp4_enc(acc[ct][2]) << 8) | (fp4_enc(acc[ct][3]) << 12);
            ldsO[lrow * 32 + 4 * ct + kg] = (unsigned short)c;
        }
        __syncthreads();

        // coalesced out: 16 KB per block = 1024 threads x 16 B
        if (row0 + (t >> 2) < N)
            *(uint4*)((char*)hs4 + (size_t)row0 * 64 + t * 16) = ((const uint4*)ldsO)[t];
        return;
    }

    // ================= SCAN role =================
    int* cnt    = (int*)sm;            // 1024 ints
    int* runpos = (int*)(sm + 4096);   // 1024 ints
    int* sdst   = (int*)(sm + 8192);   // SCHUNK ints (12.8 KB)
    float* smf  = (float*)(sm + 8192 + SCHUNK * 4);  // 16 floats

    for (int i = t; i < NBK; i += 1024) cnt[i] = 0;
    __syncthreads();
    int chunk = ((E + SCANB - 1) / SCANB + 3) & ~3;  // mult of 4 (3128 at E=1.6M)
    bool fits = (chunk <= SCHUNK);
    int e0 = blockIdx.x * chunk, e1 = min(e0 + chunk, E);
    int nv = max(0, e1 - e0) & ~3;

    // phase 1: count (and stage dst into LDS)
    for (int e = e0 + t * 4; e < e0 + nv; e += 1024 * 4) {
        int4 d4 = *(const int4*)(dst + e);
        if (fits) *(int4*)(sdst + (e - e0)) = d4;
        atomicAdd(&cnt[d4.x >> 6], 1);
        atomicAdd(&cnt[d4.y >> 6], 1);
        atomicAdd(&cnt[d4.z >> 6], 1);
        atomicAdd(&cnt[d4.w >> 6], 1);
    }
    for (int e = e0 + nv + t; e < e1; e += 1024) {
        int d = dst[e];
        if (fits) sdst[e - e0] = d;
        atomicAdd(&cnt[d >> 6], 1);
    }
    __syncthreads();

    // phase 2: reserve runs (one global atomic per non-empty bucket)
    for (int i = t; i < NBK; i += 1024) {
        int c = cnt[i];
        runpos[i] = (c > 0) ? atomicAdd(&bucketCursor[i], c) : 0;
    }
    __syncthreads();

    // phase 3: write records + softmax partial sum
    float s = 0.0f;
    for (int e = e0 + t * 4; e < e0 + nv; e += 1024 * 4) {
        int4   d4 = fits ? *(const int4*)(sdst + (e - e0)) : *(const int4*)(dst + e);
        int4   s4 = *(const int4*)(src + e);
        float4 f4 = *(const float4*)(ef + e);
        {
            float w = expf(f4.x); s += w;
            int bk = d4.x >> 6;
            int p = atomicAdd(&runpos[bk], 1);
            if (p < (bk + 1) * CAP)
                __builtin_nontemporal_store(
                    ((ull)(uint)__float_as_int(w) << 32) | ((uint)(d4.x & 63) << 20) | (uint)s4.x,
                    &ebin[p]);
        }
        {
            float w = expf(f4.y); s += w;
            int bk = d4.y >> 6;
            int p = atomicAdd(&runpos[bk], 1);
            if (p < (bk + 1) * CAP)
                __builtin_nontemporal_store(
                    ((ull)(uint)__float_as_int(w) << 32) | ((uint)(d4.y & 63) << 20) | (uint)s4.y,
                    &ebin[p]);
        }
        {
            float w = expf(f4.z); s += w;
            int bk = d4.z >> 6;
            int p = atomicAdd(&runpos[bk], 1);
            if (p < (bk + 1) * CAP)
                __builtin_nontemporal_store(
                    ((ull)(uint)__float_as_int(w) << 32) | ((uint)(d4.z & 63) << 20) | (uint)s4.z,
                    &ebin[p]);
        }
        {
            float w = expf(f4.w); s += w;
            int bk = d4.w >> 6;
            int p = atomicAdd(&runpos[bk], 1);
            if (p < (bk + 1) * CAP)
                __builtin_nontemporal_store(
                    ((ull)(uint)__float_as_int(w) << 32) | ((uint)(d4.w & 63) << 20) | (uint)s4.w,
                    &ebin[p]);
        }
    }
    for (int e = e0 + nv + t; e < e1; e += 1024) {
        int d = fits ? sdst[e - e0] : dst[e];
        int sv = src[e];
        float w = expf(ef[e]); s += w;
        int bk = d >> 6;
        int p = atomicAdd(&runpos[bk], 1);
        if (p < (bk + 1) * CAP)
            __builtin_nontemporal_store(
                ((ull)(uint)__float_as_int(w) << 32) | ((uint)(d & 63) << 20) | (uint)sv,
                &ebin[p]);
    }

    // block-reduce s -> scal[1]
    #pragma unroll
    for (int o = 32; o > 0; o >>= 1) s += __shfl_down(s, o, 64);
    int lane = t & 63, wid = t >> 6;
    if (lane == 0) smf[wid] = s;
    __syncthreads();
    if (wid == 0) {
        float v = (lane < 16) ? smf[lane] : 0.0f;
        #pragma unroll
        for (int o = 8; o > 0; o >>= 1) v += __shfl_down(v, o, 64);
        if (lane == 0) atomicAdd(scal + 1, v);
    }
}

// kD: fused LDS-sort + gather. One block per 64-dst bucket.
__global__ __launch_bounds__(1024) void k_fused(const int* __restrict__ bucketCursor,
                                                const ull* __restrict__ ebin,
                                                const uint* __restrict__ hs4,
                                                const float* __restrict__ bias,
                                                const float* __restrict__ scal,
                                                float* __restrict__ out, int N) {
    extern __shared__ ull smem[];
    ull* stage  = smem;            // CAP
    ull* sorted = smem + CAP;      // CAP
    int* cnt = (int*)(smem + 2 * CAP);  // 64
    int* cur = cnt + 64;                // 64
    int* seg = cur + 64;                // 64 (inclusive scan)
    int b = blockIdx.x;
    int base = b * CAP;
    int m = min(bucketCursor[b] - base, CAP);
    int t = threadIdx.x;
    if (t < 64) cnt[t] = 0;
    __syncthreads();
    for (int i = t; i < m; i += 1024) {
        ull v = __builtin_nontemporal_load(&ebin[base + i]);
        stage[i] = v;
        atomicAdd(&cnt[(uint)(v >> 20) & 63u], 1);
    }
    __syncthreads();
    // wave-0 shuffle scan of the 64 counters (1 barrier instead of 13)
    if (t < 64) {
        int v = cnt[t];
        int sc = v;
        #pragma unroll
        for (int o = 1; o < 64; o <<= 1) {
            int u = __shfl_up(sc, o, 64);
            if (t >= o) sc += u;
        }
        seg[t] = sc;        // inclusive scan
        cur[t] = sc - v;    // exclusive
    }
    __syncthreads();
    for (int i = t; i < m; i += 1024) {
        ull v = stage[i];
        int dl = (int)((uint)(v >> 20) & 63u);
        int p = atomicAdd(&cur[dl], 1);
        sorted[p] = v;
    }
    __syncthreads();
    int wave = t >> 6, lane = t & 63;
    int dl = wave * 4 + (lane >> 4);
    int g = lane & 15;
    int d = b * 64 + dl;
    int c = cnt[dl];
    int s0 = seg[dl] - c;
    float inv = 1.0f / scal[1];
    float acc[8];
    #pragma unroll
    for (int k = 0; k < 8; ++k) acc[k] = 0.0f;
    int j = 0;
    for (; j + 1 < c; j += 2) {
        ull v0 = sorted[s0 + j];
        ull v1 = sorted[s0 + j + 1];
        uint q0 = hs4[(size_t)(uint)(v0 & 0xfffffu) * 16 + g];
        uint q1 = hs4[(size_t)(uint)(v1 & 0xfffffu) * 16 + g];
        float w0 = __uint_as_float((uint)(v0 >> 32));
        float w1 = __uint_as_float((uint)(v1 >> 32));
        dec8_fma(q0, w0, acc);
        dec8_fma(q1, w1, acc);
    }
    if (j < c) {
        ull v = sorted[s0 + j];
        uint q = hs4[(size_t)(uint)(v & 0xfffffu) * 16 + g];
        float w = __uint_as_float((uint)(v >> 32));
        dec8_fma(q, w, acc);
    }
    if (d < N) {
        const float4* b4 = (const float4*)(bias + g * 8);
        float* o = out + (size_t)d * F + g * 8;
        #pragma unroll
        for (int k = 0; k < 2; ++k) {
            float4 bs = b4[k];
            f32x4 r;
            r.x = bs.x + inv * acc[4 * k + 0];
            r.y = bs.y + inv * acc[4 * k + 1];
            r.z = bs.z + inv * acc[4 * k + 2];
            r.w = bs.w + inv * acc[4 * k + 3];
            __builtin_nontemporal_store(r, (f32x4*)(o + 4 * k));
        }
    }
}

// ---------- launch ----------
extern "C" void kernel_launch(void* const* d_in, const int* in_sizes, int n_in,
                              void* d_out, int out_size, void* d_ws, size_t ws_size,
                              hipStream_t stream) {
    const float* h    = (const float*)d_in[0];
    const float* ef   = (const float*)d_in[1];
    const int*   src  = (const int*)d_in[2];
    const int*   dst  = (const int*)d_in[3];
    const float* W    = (const float*)d_in[4];
    const float* bias = (const float*)d_in[5];
    float*       out  = (float*)d_out;

    int N = in_sizes[0] / F;        // 50000
    int E = in_sizes[1];            // 1.6M
    int NBK = (N + 63) >> 6;        // 782 buckets of 64 dsts
    int GB  = (N + 255) >> 8;       // 196 gemm-role blocks (256 rows each)

    // workspace layout
    char*  base = (char*)d_ws;
    float* scal  = (float*)base;                     base += 16 * sizeof(float);
    unsigned short* WT = (unsigned short*)base;      base += F * F * sizeof(unsigned short);
    ull*   ebin  = (ull*)base;                       base += (size_t)NBK * CAP * sizeof(ull);
    unsigned short* hs4 = (unsigned short*)base;     base += (size_t)N * 64;  // fp4: 64 B/row
    int*   bucketCursor = (int*)base;

    size_t fusedLds = (size_t)2 * CAP * 8 + 3 * 64 * 4;

    hipLaunchKernelGGL(k_setup, dim3(64), dim3(256), 0, stream, scal, bucketCursor, W, WT, NBK);
    hipLaunchKernelGGL(k_main,  dim3(SCANB + GB), dim3(1024), 0, stream,
                       h, WT, hs4, N, src, dst, ef, E, NBK, bucketCursor, ebin, scal);
    hipLaunchKernelGGL(k_fused, dim3(NBK), dim3(1024), fusedLds, stream,
                       bucketCursor, ebin, (const uint*)hs4, bias, scal, out, N);
}

// Round 7
// 154.926 us; speedup vs baseline: 1.2825x; 1.2825x over previous
//
#include <hip/hip_runtime.h>
#include <math.h>

#define F 128
#define CAP 2688     // max edges per 64-dst bucket (mean 2048, sigma ~45 -> +14 sigma)
#define SCHUNK 6400  // per-block dst LDS staging capacity (E/256 = 6250 at E=1.6M)
#define SCANB 256    // scan-role blocks (chunk ~6250 -> run length ~8 recs; r6 showed shorter runs amplify writes)
typedef unsigned long long ull;
typedef unsigned int uint;
typedef float f32x4 __attribute__((ext_vector_type(4)));
typedef short bf16x8 __attribute__((ext_vector_type(8)));   // 8 bf16 = 4 VGPRs (guide §3)

// edge record in ebin: [w:32][dlow:6][src:20]  (src < 2^20, dlow = dst & 63)
// ebin layout: bucket b owns slots [b*CAP, (b+1)*CAP); cursor[b]-b*CAP = count
// ebin stores are PLAIN (not nontemporal): consumed by k_fused soon after; L2
// residency + write-combining matter (r6: nt stores -> +49MB WRITE, +46us).
// hs4: fp4 e2m1 (global scale 2), 128 feats x 4 bits = 64 B/row -> 3.2 MB total
// WT : bf16 transpose of (W[0]+W[1]), [n][k] layout, 32 KB (L1/L2-resident)

// ---------- fp4 helpers ----------
__device__ __forceinline__ uint fp4_enc(float v) {
    uint s = (__float_as_uint(v) >> 28) & 8u;
    float af = fabsf(v);
    uint c = af < 0.5f ? 0u : af < 1.5f ? 1u : af < 2.5f ? 2u : af < 3.5f ? 3u
           : af < 5.0f ? 4u : af < 7.0f ? 5u : af < 10.0f ? 6u : 7u;
    return s | c;
}

#if __has_builtin(__builtin_amdgcn_cvt_scalef32_pk_f32_fp4)
__device__ __forceinline__ void dec8_fma(uint x, float w, float* acc) {
    auto p0 = __builtin_amdgcn_cvt_scalef32_pk_f32_fp4(x, 2.0f, 0);
    auto p1 = __builtin_amdgcn_cvt_scalef32_pk_f32_fp4(x, 2.0f, 1);
    auto p2 = __builtin_amdgcn_cvt_scalef32_pk_f32_fp4(x, 2.0f, 2);
    auto p3 = __builtin_amdgcn_cvt_scalef32_pk_f32_fp4(x, 2.0f, 3);
    acc[0] += w * p0[0]; acc[1] += w * p0[1];
    acc[2] += w * p1[0]; acc[3] += w * p1[1];
    acc[4] += w * p2[0]; acc[5] += w * p2[1];
    acc[6] += w * p3[0]; acc[7] += w * p3[1];
}
#else
__device__ __forceinline__ uint fp4x4_to_fp8x4(uint b) {
    uint mag = b & 0x07070707u;
    uint sgn = (b & 0x08080808u) << 4;
    uint g2  = ((mag >> 1) | (mag >> 2)) & 0x01010101u;
    uint msk = g2 * 0xFFu;
    uint A   = 0x30303030u + (mag << 2);
    uint B   = (mag & 0x01010101u) * 0x30u;
    return sgn | (msk & A) | (~msk & B);
}
__device__ __forceinline__ void dec8_fma(uint x, float w, float* acc) {
    uint lo = x & 0x0F0F0F0Fu;
    uint hi = (x >> 4) & 0x0F0F0F0Fu;
    uint f8l = fp4x4_to_fp8x4(lo);
    uint f8h = fp4x4_to_fp8x4(hi);
    auto p0 = __builtin_amdgcn_cvt_pk_f32_fp8(f8l, false);
    auto p1 = __builtin_amdgcn_cvt_pk_f32_fp8(f8l, true);
    auto p2 = __builtin_amdgcn_cvt_pk_f32_fp8(f8h, false);
    auto p3 = __builtin_amdgcn_cvt_pk_f32_fp8(f8h, true);
    float w2 = w * 2.0f;
    acc[0] += w2 * p0[0]; acc[2] += w2 * p0[1]; acc[4] += w2 * p1[0]; acc[6] += w2 * p1[1];
    acc[1] += w2 * p2[0]; acc[3] += w2 * p2[1]; acc[5] += w2 * p3[0]; acc[7] += w2 * p3[1];
}
#endif

// float -> bf16 (RNE), pack two into a uint
__device__ __forceinline__ uint pk_bf16(float a, float b) {
    uint ua = __float_as_uint(a); ua = (ua + 0x7FFFu + ((ua >> 16) & 1u)) >> 16;
    uint ub = __float_as_uint(b); ub = (ub + 0x7FFFu + ((ub >> 16) & 1u)) >> 16;
    return ua | (ub << 16);
}

// ---------- kernels ----------
// setup: WT[n][k] = bf16(W[0][k][n] + W[1][k][n]); cursor[i] = i*CAP; scal = 0
__global__ void k_setup(float* __restrict__ scal, int* __restrict__ bucketCursor,
                        const float* __restrict__ W, unsigned short* __restrict__ WT, int NBK) {
    int i = blockIdx.x * 256 + threadIdx.x;
    if (i < F * F) {
        int k = i >> 7, n = i & 127;
        float v = W[i] + W[F * F + i];
        uint u = __float_as_uint(v);
        u = (u + 0x7FFFu + ((u >> 16) & 1u)) >> 16;
        WT[n * F + k] = (unsigned short)u;
    }
    if (i < 16) scal[i] = 0.0f;
    if (i < NBK) bucketCursor[i] = i * CAP;
}

// k_main: heterogeneous roles in one dispatch.
//   blocks [0, SCANB):         edge scan -> packed ebin records + softmax denom
//   blocks [SCANB, SCANB+GB):  256-row bf16-MFMA tile of hs4 = fp4(h @ Wsum)
// 64 KB LDS -> 2 blocks/CU resident; 452 blocks <= 512 slots, all co-resident.
// launch_bounds (1024,4): VGPR cap 64 = gemm role's natural usage (r2: 64, no spill).
__global__ __launch_bounds__(1024, 4) void k_main(const float* __restrict__ h,
                                                  const unsigned short* __restrict__ WT,
                                                  unsigned short* __restrict__ hs4, int N,
                                                  const int* __restrict__ src,
                                                  const int* __restrict__ dst,
                                                  const float* __restrict__ ef, int E, int NBK,
                                                  int* __restrict__ bucketCursor,
                                                  ull* __restrict__ ebin,
                                                  float* __restrict__ scal) {
    __shared__ __align__(16) char sm[65536];   // union: scan ~34KB | gemm 64KB (ldsA reused as ldsO)
    int t = threadIdx.x;

    if (blockIdx.x >= SCANB) {
        // ================= GEMM role: 256 rows/block, 16 waves =================
        char* ldsA = sm;   // 256 rows x 256 B (bf16, XOR-swizzled); reused for fp4 out after MFMA
        int row0 = (int)(blockIdx.x - SCANB) * 256;

        // stage h tile -> bf16 LDS; chunk = 16 B (8 feats); byte ^= (row&7)<<4 (G4 swizzle)
        for (int c = t; c < 256 * 16; c += 1024) {
            int r = c >> 4, cc = c & 15;
            float4 v0 = make_float4(0.f, 0.f, 0.f, 0.f), v1 = v0;
            if (row0 + r < N) {
                const float4* hp = (const float4*)(h + (size_t)(row0 + r) * F + cc * 8);
                v0 = hp[0]; v1 = hp[1];
            }
            uint4 b;
            b.x = pk_bf16(v0.x, v0.y); b.y = pk_bf16(v0.z, v0.w);
            b.z = pk_bf16(v1.x, v1.y); b.w = pk_bf16(v1.z, v1.w);
            *(uint4*)(ldsA + (r * 256 + ((cc * 16) ^ ((r & 7) << 4)))) = b;
        }
        __syncthreads();

        int lane = t & 63, wid = t >> 6;
        int lr = lane & 15;        // row within wave's 16-row slice / WT row within n-tile
        int kg = lane >> 4;        // k-group 0..3 (8 bf16 each)
        int lrow = wid * 16 + lr;  // LDS row 0..255

        f32x4 acc[8];
        #pragma unroll
        for (int ct = 0; ct < 8; ++ct) acc[ct] = (f32x4){0.f, 0.f, 0.f, 0.f};

        #pragma unroll
        for (int ks = 0; ks < 4; ++ks) {
            bf16x8 bh = *(const bf16x8*)(ldsA + (lrow * 256 + ((ks * 64 + kg * 16) ^ ((lrow & 7) << 4))));
            #pragma unroll
            for (int ct = 0; ct < 8; ++ct) {
                bf16x8 aw = *(const bf16x8*)(WT + (size_t)(16 * ct + lr) * F + ks * 32 + kg * 8);
                acc[ct] = __builtin_amdgcn_mfma_f32_16x16x32_bf16(aw, bh, acc[ct], 0, 0, 0);
            }
        }
        __syncthreads();   // all ds_reads of ldsA consumed into acc -> safe to reuse

        // pack fp4 nibbles into reused LDS: lane holds 4 consecutive cols per tile
        unsigned short* ldsO = (unsigned short*)sm;   // 256 rows x 64 B fp4 (16 KB)
        #pragma unroll
        for (int ct = 0; ct < 8; ++ct) {
            uint c = fp4_enc(acc[ct][0]) | (fp4_enc(acc[ct][1]) << 4)
                   | (fp4_enc(acc[ct][2]) << 8) | (fp4_enc(acc[ct][3]) << 12);
            ldsO[lrow * 32 + 4 * ct + kg] = (unsigned short)c;
        }
        __syncthreads();

        // coalesced out: 16 KB per block = 1024 threads x 16 B
        if (row0 + (t >> 2) < N)
            *(uint4*)((char*)hs4 + (size_t)row0 * 64 + t * 16) = ((const uint4*)ldsO)[t];
        return;
    }

    // ================= SCAN role =================
    int* cnt    = (int*)sm;            // 1024 ints
    int* runpos = (int*)(sm + 4096);   // 1024 ints
    int* sdst   = (int*)(sm + 8192);   // SCHUNK ints (25.6 KB)
    float* smf  = (float*)(sm + 8192 + SCHUNK * 4);  // 16 floats

    for (int i = t; i < NBK; i += 1024) cnt[i] = 0;
    __syncthreads();
    int chunk = ((E + SCANB - 1) / SCANB + 3) & ~3;  // mult of 4 (6252 at E=1.6M)
    bool fits = (chunk <= SCHUNK);
    int e0 = blockIdx.x * chunk, e1 = min(e0 + chunk, E);
    int nv = max(0, e1 - e0) & ~3;

    // phase 1: count (and stage dst into LDS)
    for (int e = e0 + t * 4; e < e0 + nv; e += 1024 * 4) {
        int4 d4 = *(const int4*)(dst + e);
        if (fits) *(int4*)(sdst + (e - e0)) = d4;
        atomicAdd(&cnt[d4.x >> 6], 1);
        atomicAdd(&cnt[d4.y >> 6], 1);
        atomicAdd(&cnt[d4.z >> 6], 1);
        atomicAdd(&cnt[d4.w >> 6], 1);
    }
    for (int e = e0 + nv + t; e < e1; e += 1024) {
        int d = dst[e];
        if (fits) sdst[e - e0] = d;
        atomicAdd(&cnt[d >> 6], 1);
    }
    __syncthreads();

    // phase 2: reserve runs (one global atomic per non-empty bucket)
    for (int i = t; i < NBK; i += 1024) {
        int c = cnt[i];
        runpos[i] = (c > 0) ? atomicAdd(&bucketCursor[i], c) : 0;
    }
    __syncthreads();

    // phase 3: write records + softmax partial sum
    float s = 0.0f;
    for (int e = e0 + t * 4; e < e0 + nv; e += 1024 * 4) {
        int4   d4 = fits ? *(const int4*)(sdst + (e - e0)) : *(const int4*)(dst + e);
        int4   s4 = *(const int4*)(src + e);
        float4 f4 = *(const float4*)(ef + e);
        {
            float w = expf(f4.x); s += w;
            int bk = d4.x >> 6;
            int p = atomicAdd(&runpos[bk], 1);
            if (p < (bk + 1) * CAP)
                ebin[p] = ((ull)(uint)__float_as_int(w) << 32) | ((uint)(d4.x & 63) << 20) | (uint)s4.x;
        }
        {
            float w = expf(f4.y); s += w;
            int bk = d4.y >> 6;
            int p = atomicAdd(&runpos[bk], 1);
            if (p < (bk + 1) * CAP)
                ebin[p] = ((ull)(uint)__float_as_int(w) << 32) | ((uint)(d4.y & 63) << 20) | (uint)s4.y;
        }
        {
            float w = expf(f4.z); s += w;
            int bk = d4.z >> 6;
            int p = atomicAdd(&runpos[bk], 1);
            if (p < (bk + 1) * CAP)
                ebin[p] = ((ull)(uint)__float_as_int(w) << 32) | ((uint)(d4.z & 63) << 20) | (uint)s4.z;
        }
        {
            float w = expf(f4.w); s += w;
            int bk = d4.w >> 6;
            int p = atomicAdd(&runpos[bk], 1);
            if (p < (bk + 1) * CAP)
                ebin[p] = ((ull)(uint)__float_as_int(w) << 32) | ((uint)(d4.w & 63) << 20) | (uint)s4.w;
        }
    }
    for (int e = e0 + nv + t; e < e1; e += 1024) {
        int d = fits ? sdst[e - e0] : dst[e];
        int sv = src[e];
        float w = expf(ef[e]); s += w;
        int bk = d >> 6;
        int p = atomicAdd(&runpos[bk], 1);
        if (p < (bk + 1) * CAP)
            ebin[p] = ((ull)(uint)__float_as_int(w) << 32) | ((uint)(d & 63) << 20) | (uint)sv;
    }

    // block-reduce s -> scal[1]
    #pragma unroll
    for (int o = 32; o > 0; o >>= 1) s += __shfl_down(s, o, 64);
    int lane = t & 63, wid = t >> 6;
    if (lane == 0) smf[wid] = s;
    __syncthreads();
    if (wid == 0) {
        float v = (lane < 16) ? smf[lane] : 0.0f;
        #pragma unroll
        for (int o = 8; o > 0; o >>= 1) v += __shfl_down(v, o, 64);
        if (lane == 0) atomicAdd(scal + 1, v);
    }
}

// kD: fused LDS-sort + gather. One block per 64-dst bucket.
// Gather loop unrolled x4: 4 independent {ds_read sorted -> hs4 load} chains in
// flight per 16-lane group (was x2) to cover the ~120cy LDS + ~250cy L2 latency.
__global__ __launch_bounds__(1024) void k_fused(const int* __restrict__ bucketCursor,
                                                const ull* __restrict__ ebin,
                                                const uint* __restrict__ hs4,
                                                const float* __restrict__ bias,
                                                const float* __restrict__ scal,
                                                float* __restrict__ out, int N) {
    extern __shared__ ull smem[];
    ull* stage  = smem;            // CAP
    ull* sorted = smem + CAP;      // CAP
    int* cnt = (int*)(smem + 2 * CAP);  // 64
    int* cur = cnt + 64;                // 64
    int* seg = cur + 64;                // 64 (inclusive scan)
    int b = blockIdx.x;
    int base = b * CAP;
    int m = min(bucketCursor[b] - base, CAP);
    int t = threadIdx.x;
    if (t < 64) cnt[t] = 0;
    __syncthreads();
    for (int i = t; i < m; i += 1024) {
        ull v = __builtin_nontemporal_load(&ebin[base + i]);
        stage[i] = v;
        atomicAdd(&cnt[(uint)(v >> 20) & 63u], 1);
    }
    __syncthreads();
    // wave-0 shuffle scan of the 64 counters (1 barrier instead of 13)
    if (t < 64) {
        int v = cnt[t];
        int sc = v;
        #pragma unroll
        for (int o = 1; o < 64; o <<= 1) {
            int u = __shfl_up(sc, o, 64);
            if (t >= o) sc += u;
        }
        seg[t] = sc;        // inclusive scan
        cur[t] = sc - v;    // exclusive
    }
    __syncthreads();
    for (int i = t; i < m; i += 1024) {
        ull v = stage[i];
        int dl = (int)((uint)(v >> 20) & 63u);
        int p = atomicAdd(&cur[dl], 1);
        sorted[p] = v;
    }
    __syncthreads();
    int wave = t >> 6, lane = t & 63;
    int dl = wave * 4 + (lane >> 4);
    int g = lane & 15;
    int d = b * 64 + dl;
    int c = cnt[dl];
    int s0 = seg[dl] - c;
    float inv = 1.0f / scal[1];
    float acc[8];
    #pragma unroll
    for (int k = 0; k < 8; ++k) acc[k] = 0.0f;
    int j = 0;
    for (; j + 3 < c; j += 4) {
        ull v0 = sorted[s0 + j];
        ull v1 = sorted[s0 + j + 1];
        ull v2 = sorted[s0 + j + 2];
        ull v3 = sorted[s0 + j + 3];
        uint q0 = hs4[(size_t)(uint)(v0 & 0xfffffu) * 16 + g];
        uint q1 = hs4[(size_t)(uint)(v1 & 0xfffffu) * 16 + g];
        uint q2 = hs4[(size_t)(uint)(v2 & 0xfffffu) * 16 + g];
        uint q3 = hs4[(size_t)(uint)(v3 & 0xfffffu) * 16 + g];
        dec8_fma(q0, __uint_as_float((uint)(v0 >> 32)), acc);
        dec8_fma(q1, __uint_as_float((uint)(v1 >> 32)), acc);
        dec8_fma(q2, __uint_as_float((uint)(v2 >> 32)), acc);
        dec8_fma(q3, __uint_as_float((uint)(v3 >> 32)), acc);
    }
    for (; j < c; ++j) {
        ull v = sorted[s0 + j];
        uint q = hs4[(size_t)(uint)(v & 0xfffffu) * 16 + g];
        float w = __uint_as_float((uint)(v >> 32));
        dec8_fma(q, w, acc);
    }
    if (d < N) {
        const float4* b4 = (const float4*)(bias + g * 8);
        float* o = out + (size_t)d * F + g * 8;
        #pragma unroll
        for (int k = 0; k < 2; ++k) {
            float4 bs = b4[k];
            f32x4 r;
            r.x = bs.x + inv * acc[4 * k + 0];
            r.y = bs.y + inv * acc[4 * k + 1];
            r.z = bs.z + inv * acc[4 * k + 2];
            r.w = bs.w + inv * acc[4 * k + 3];
            __builtin_nontemporal_store(r, (f32x4*)(o + 4 * k));
        }
    }
}

// ---------- launch ----------
extern "C" void kernel_launch(void* const* d_in, const int* in_sizes, int n_in,
                              void* d_out, int out_size, void* d_ws, size_t ws_size,
                              hipStream_t stream) {
    const float* h    = (const float*)d_in[0];
    const float* ef   = (const float*)d_in[1];
    const int*   src  = (const int*)d_in[2];
    const int*   dst  = (const int*)d_in[3];
    const float* W    = (const float*)d_in[4];
    const float* bias = (const float*)d_in[5];
    float*       out  = (float*)d_out;

    int N = in_sizes[0] / F;        // 50000
    int E = in_sizes[1];            // 1.6M
    int NBK = (N + 63) >> 6;        // 782 buckets of 64 dsts
    int GB  = (N + 255) >> 8;       // 196 gemm-role blocks (256 rows each)

    // workspace layout
    char*  base = (char*)d_ws;
    float* scal  = (float*)base;                     base += 16 * sizeof(float);
    unsigned short* WT = (unsigned short*)base;      base += F * F * sizeof(unsigned short);
    ull*   ebin  = (ull*)base;                       base += (size_t)NBK * CAP * sizeof(ull);
    unsigned short* hs4 = (unsigned short*)base;     base += (size_t)N * 64;  // fp4: 64 B/row
    int*   bucketCursor = (int*)base;

    size_t fusedLds = (size_t)2 * CAP * 8 + 3 * 64 * 4;

    hipLaunchKernelGGL(k_setup, dim3(64), dim3(256), 0, stream, scal, bucketCursor, W, WT, NBK);
    hipLaunchKernelGGL(k_main,  dim3(SCANB + GB), dim3(1024), 0, stream,
                       h, WT, hs4, N, src, dst, ef, E, NBK, bucketCursor, ebin, scal);
    hipLaunchKernelGGL(k_fused, dim3(NBK), dim3(1024), fusedLds, stream,
                       bucketCursor, ebin, (const uint*)hs4, bias, scal, out, N);
}

// Round 10
// 147.911 us; speedup vs baseline: 1.3434x; 1.0474x over previous
//
#include <hip/hip_runtime.h>
#include <math.h>

#define F 128
#define CAP 2688     // max edges per 64-dst bucket (mean 2048, sigma ~45 -> +14 sigma)
#define SCHUNK 3200  // per-block dst LDS staging capacity (E/512 = 3128 at E=1.6M)
#define SCANB 512    // scan-role blocks: 512 = full residency (2 blk/CU, 32 waves/CU)
typedef unsigned long long ull;
typedef unsigned int uint;
typedef float f32x4 __attribute__((ext_vector_type(4)));
typedef short bf16x8 __attribute__((ext_vector_type(8)));   // 8 bf16 = 4 VGPRs (guide §3)

// edge record in ebin: [w:32][dlow:6][src:20]  (src < 2^20, dlow = dst & 63)
// ebin layout: bucket b owns slots [b*CAP, (b+1)*CAP); cursor[b]-b*CAP = count
// ebin stores are PLAIN (not nontemporal): consumed by k_fused soon after; L2
// residency + write-combining matter (r6: nt stores -> +49MB WRITE, +46us).
// Block order: GEMM blocks FIRST (drain fast, free residency slots for scan).
// hs4: fp4 e2m1 (global scale 2), 128 feats x 4 bits = 64 B/row -> 3.2 MB total
// WT : bf16 transpose of (W[0]+W[1]), [n][k] layout, 32 KB (L1/L2-resident)

// ---------- fp4 helpers ----------
__device__ __forceinline__ uint fp4_enc(float v) {
    uint s = (__float_as_uint(v) >> 28) & 8u;
    float af = fabsf(v);
    uint c = af < 0.5f ? 0u : af < 1.5f ? 1u : af < 2.5f ? 2u : af < 3.5f ? 3u
           : af < 5.0f ? 4u : af < 7.0f ? 5u : af < 10.0f ? 6u : 7u;
    return s | c;
}

#if __has_builtin(__builtin_amdgcn_cvt_scalef32_pk_f32_fp4)
__device__ __forceinline__ void dec8_fma(uint x, float w, float* acc) {
    auto p0 = __builtin_amdgcn_cvt_scalef32_pk_f32_fp4(x, 2.0f, 0);
    auto p1 = __builtin_amdgcn_cvt_scalef32_pk_f32_fp4(x, 2.0f, 1);
    auto p2 = __builtin_amdgcn_cvt_scalef32_pk_f32_fp4(x, 2.0f, 2);
    auto p3 = __builtin_amdgcn_cvt_scalef32_pk_f32_fp4(x, 2.0f, 3);
    acc[0] += w * p0[0]; acc[1] += w * p0[1];
    acc[2] += w * p1[0]; acc[3] += w * p1[1];
    acc[4] += w * p2[0]; acc[5] += w * p2[1];
    acc[6] += w * p3[0]; acc[7] += w * p3[1];
}
#else
__device__ __forceinline__ uint fp4x4_to_fp8x4(uint b) {
    uint mag = b & 0x07070707u;
    uint sgn = (b & 0x08080808u) << 4;
    uint g2  = ((mag >> 1) | (mag >> 2)) & 0x01010101u;
    uint msk = g2 * 0xFFu;
    uint A   = 0x30303030u + (mag << 2);
    uint B   = (mag & 0x01010101u) * 0x30u;
    return sgn | (msk & A) | (~msk & B);
}
__device__ __forceinline__ void dec8_fma(uint x, float w, float* acc) {
    uint lo = x & 0x0F0F0F0Fu;
    uint hi = (x >> 4) & 0x0F0F0F0Fu;
    uint f8l = fp4x4_to_fp8x4(lo);
    uint f8h = fp4x4_to_fp8x4(hi);
    auto p0 = __builtin_amdgcn_cvt_pk_f32_fp8(f8l, false);
    auto p1 = __builtin_amdgcn_cvt_pk_f32_fp8(f8l, true);
    auto p2 = __builtin_amdgcn_cvt_pk_f32_fp8(f8h, false);
    auto p3 = __builtin_amdgcn_cvt_pk_f32_fp8(f8h, true);
    float w2 = w * 2.0f;
    acc[0] += w2 * p0[0]; acc[2] += w2 * p0[1]; acc[4] += w2 * p1[0]; acc[6] += w2 * p1[1];
    acc[1] += w2 * p2[0]; acc[3] += w2 * p2[1]; acc[5] += w2 * p3[0]; acc[7] += w2 * p3[1];
}
#endif

// float -> bf16 (RNE), pack two into a uint
__device__ __forceinline__ uint pk_bf16(float a, float b) {
    uint ua = __float_as_uint(a); ua = (ua + 0x7FFFu + ((ua >> 16) & 1u)) >> 16;
    uint ub = __float_as_uint(b); ub = (ub + 0x7FFFu + ((ub >> 16) & 1u)) >> 16;
    return ua | (ub << 16);
}

// ---------- kernels ----------
// setup: WT[n][k] = bf16(W[0][k][n] + W[1][k][n]); cursor[i] = i*CAP; scal = 0
__global__ void k_setup(float* __restrict__ scal, int* __restrict__ bucketCursor,
                        const float* __restrict__ W, unsigned short* __restrict__ WT, int NBK) {
    int i = blockIdx.x * 256 + threadIdx.x;
    if (i < F * F) {
        int k = i >> 7, n = i & 127;
        float v = W[i] + W[F * F + i];
        uint u = __float_as_uint(v);
        u = (u + 0x7FFFu + ((u >> 16) & 1u)) >> 16;
        WT[n * F + k] = (unsigned short)u;
    }
    if (i < 16) scal[i] = 0.0f;
    if (i < NBK) bucketCursor[i] = i * CAP;
}

// k_main: heterogeneous roles in one dispatch.
//   blocks [0, GB):            256-row bf16-MFMA tile of hs4 = fp4(h @ Wsum)
//   blocks [GB, GB+SCANB):     edge scan -> packed ebin records + softmax denom
// GEMM first: 708 blocks > 512 residency slots (16-wave blocks, 32-wave/CU cap);
// gemm drains quickly, freeing slots so the scan runs ~2 blocks/CU (32 waves/CU).
// launch_bounds (1024,4): VGPR cap 64 = gemm role's natural usage (r2: 64, no spill).
__global__ __launch_bounds__(1024, 4) void k_main(const float* __restrict__ h,
                                                  const unsigned short* __restrict__ WT,
                                                  unsigned short* __restrict__ hs4, int N, int GB,
                                                  const int* __restrict__ src,
                                                  const int* __restrict__ dst,
                                                  const float* __restrict__ ef, int E, int NBK,
                                                  int* __restrict__ bucketCursor,
                                                  ull* __restrict__ ebin,
                                                  float* __restrict__ scal) {
    __shared__ __align__(16) char sm[65536];   // union: scan ~21KB | gemm 64KB (ldsA reused as ldsO)
    int t = threadIdx.x;

    if (blockIdx.x < GB) {
        // ================= GEMM role: 256 rows/block, 16 waves =================
        char* ldsA = sm;   // 256 rows x 256 B (bf16, XOR-swizzled); reused for fp4 out after MFMA
        int row0 = (int)blockIdx.x * 256;

        // stage h tile -> bf16 LDS; chunk = 16 B (8 feats); byte ^= (row&7)<<4 (G4 swizzle)
        for (int c = t; c < 256 * 16; c += 1024) {
            int r = c >> 4, cc = c & 15;
            float4 v0 = make_float4(0.f, 0.f, 0.f, 0.f), v1 = v0;
            if (row0 + r < N) {
                const float4* hp = (const float4*)(h + (size_t)(row0 + r) * F + cc * 8);
                v0 = hp[0]; v1 = hp[1];
            }
            uint4 b;
            b.x = pk_bf16(v0.x, v0.y); b.y = pk_bf16(v0.z, v0.w);
            b.z = pk_bf16(v1.x, v1.y); b.w = pk_bf16(v1.z, v1.w);
            *(uint4*)(ldsA + (r * 256 + ((cc * 16) ^ ((r & 7) << 4)))) = b;
        }
        __syncthreads();

        int lane = t & 63, wid = t >> 6;
        int lr = lane & 15;        // row within wave's 16-row slice / WT row within n-tile
        int kg = lane >> 4;        // k-group 0..3 (8 bf16 each)
        int lrow = wid * 16 + lr;  // LDS row 0..255

        f32x4 acc[8];
        #pragma unroll
        for (int ct = 0; ct < 8; ++ct) acc[ct] = (f32x4){0.f, 0.f, 0.f, 0.f};

        #pragma unroll
        for (int ks = 0; ks < 4; ++ks) {
            bf16x8 bh = *(const bf16x8*)(ldsA + (lrow * 256 + ((ks * 64 + kg * 16) ^ ((lrow & 7) << 4))));
            #pragma unroll
            for (int ct = 0; ct < 8; ++ct) {
                bf16x8 aw = *(const bf16x8*)(WT + (size_t)(16 * ct + lr) * F + ks * 32 + kg * 8);
                acc[ct] = __builtin_amdgcn_mfma_f32_16x16x32_bf16(aw, bh, acc[ct], 0, 0, 0);
            }
        }
        __syncthreads();   // all ds_reads of ldsA consumed into acc -> safe to reuse

        // pack fp4 nibbles into reused LDS: lane holds 4 consecutive cols per tile
        unsigned short* ldsO = (unsigned short*)sm;   // 256 rows x 64 B fp4 (16 KB)
        #pragma unroll
        for (int ct = 0; ct < 8; ++ct) {
            uint c = fp4_enc(acc[ct][0]) | (fp4_enc(acc[ct][1]) << 4)
                   | (fp4_enc(acc[ct][2]) << 8) | (fp4_enc(acc[ct][3]) << 12);
            ldsO[lrow * 32 + 4 * ct + kg] = (unsigned short)c;
        }
        __syncthreads();

        // coalesced out: 16 KB per block = 1024 threads x 16 B
        if (row0 + (t >> 2) < N)
            *(uint4*)((char*)hs4 + (size_t)row0 * 64 + t * 16) = ((const uint4*)ldsO)[t];
        return;
    }

    // ================= SCAN role =================
    int bid = (int)blockIdx.x - GB;    // 0..SCANB-1
    int* cnt    = (int*)sm;            // 1024 ints
    int* runpos = (int*)(sm + 4096);   // 1024 ints
    int* sdst   = (int*)(sm + 8192);   // SCHUNK ints (12.8 KB)
    float* smf  = (float*)(sm + 8192 + SCHUNK * 4);  // 16 floats

    for (int i = t; i < NBK; i += 1024) cnt[i] = 0;
    __syncthreads();
    int chunk = ((E + SCANB - 1) / SCANB + 3) & ~3;  // mult of 4 (3128 at E=1.6M)
    bool fits = (chunk <= SCHUNK);
    int e0 = bid * chunk, e1 = min(e0 + chunk, E);
    int nv = max(0, e1 - e0) & ~3;

    // phase 1: count (and stage dst into LDS)
    for (int e = e0 + t * 4; e < e0 + nv; e += 1024 * 4) {
        int4 d4 = *(const int4*)(dst + e);
        if (fits) *(int4*)(sdst + (e - e0)) = d4;
        atomicAdd(&cnt[d4.x >> 6], 1);
        atomicAdd(&cnt[d4.y >> 6], 1);
        atomicAdd(&cnt[d4.z >> 6], 1);
        atomicAdd(&cnt[d4.w >> 6], 1);
    }
    for (int e = e0 + nv + t; e < e1; e += 1024) {
        int d = dst[e];
        if (fits) sdst[e - e0] = d;
        atomicAdd(&cnt[d >> 6], 1);
    }
    __syncthreads();

    // phase 2: reserve runs (one global atomic per non-empty bucket)
    for (int i = t; i < NBK; i += 1024) {
        int c = cnt[i];
        runpos[i] = (c > 0) ? atomicAdd(&bucketCursor[i], c) : 0;
    }
    __syncthreads();

    // phase 3: write records + softmax partial sum
    float s = 0.0f;
    for (int e = e0 + t * 4; e < e0 + nv; e += 1024 * 4) {
        int4   d4 = fits ? *(const int4*)(sdst + (e - e0)) : *(const int4*)(dst + e);
        int4   s4 = *(const int4*)(src + e);
        float4 f4 = *(const float4*)(ef + e);
        {
            float w = expf(f4.x); s += w;
            int bk = d4.x >> 6;
            int p = atomicAdd(&runpos[bk], 1);
            if (p < (bk + 1) * CAP)
                ebin[p] = ((ull)(uint)__float_as_int(w) << 32) | ((uint)(d4.x & 63) << 20) | (uint)s4.x;
        }
        {
            float w = expf(f4.y); s += w;
            int bk = d4.y >> 6;
            int p = atomicAdd(&runpos[bk], 1);
            if (p < (bk + 1) * CAP)
                ebin[p] = ((ull)(uint)__float_as_int(w) << 32) | ((uint)(d4.y & 63) << 20) | (uint)s4.y;
        }
        {
            float w = expf(f4.z); s += w;
            int bk = d4.z >> 6;
            int p = atomicAdd(&runpos[bk], 1);
            if (p < (bk + 1) * CAP)
                ebin[p] = ((ull)(uint)__float_as_int(w) << 32) | ((uint)(d4.z & 63) << 20) | (uint)s4.z;
        }
        {
            float w = expf(f4.w); s += w;
            int bk = d4.w >> 6;
            int p = atomicAdd(&runpos[bk], 1);
            if (p < (bk + 1) * CAP)
                ebin[p] = ((ull)(uint)__float_as_int(w) << 32) | ((uint)(d4.w & 63) << 20) | (uint)s4.w;
        }
    }
    for (int e = e0 + nv + t; e < e1; e += 1024) {
        int d = fits ? sdst[e - e0] : dst[e];
        int sv = src[e];
        float w = expf(ef[e]); s += w;
        int bk = d >> 6;
        int p = atomicAdd(&runpos[bk], 1);
        if (p < (bk + 1) * CAP)
            ebin[p] = ((ull)(uint)__float_as_int(w) << 32) | ((uint)(d & 63) << 20) | (uint)sv;
    }

    // block-reduce s -> scal[1]
    #pragma unroll
    for (int o = 32; o > 0; o >>= 1) s += __shfl_down(s, o, 64);
    int lane = t & 63, wid = t >> 6;
    if (lane == 0) smf[wid] = s;
    __syncthreads();
    if (wid == 0) {
        float v = (lane < 16) ? smf[lane] : 0.0f;
        #pragma unroll
        for (int o = 8; o > 0; o >>= 1) v += __shfl_down(v, o, 64);
        if (lane == 0) atomicAdd(scal + 1, v);
    }
}

// kD: fused LDS-sort + gather. One block per 64-dst bucket.
// Gather loop unrolled x4 (r7: +2us, kept).
__global__ __launch_bounds__(1024) void k_fused(const int* __restrict__ bucketCursor,
                                                const ull* __restrict__ ebin,
                                                const uint* __restrict__ hs4,
                                                const float* __restrict__ bias,
                                                const float* __restrict__ scal,
                                                float* __restrict__ out, int N) {
    extern __shared__ ull smem[];
    ull* stage  = smem;            // CAP
    ull* sorted = smem + CAP;      // CAP
    int* cnt = (int*)(smem + 2 * CAP);  // 64
    int* cur = cnt + 64;                // 64
    int* seg = cur + 64;                // 64 (inclusive scan)
    int b = blockIdx.x;
    int base = b * CAP;
    int m = min(bucketCursor[b] - base, CAP);
    int t = threadIdx.x;
    if (t < 64) cnt[t] = 0;
    __syncthreads();
    for (int i = t; i < m; i += 1024) {
        ull v = __builtin_nontemporal_load(&ebin[base + i]);
        stage[i] = v;
        atomicAdd(&cnt[(uint)(v >> 20) & 63u], 1);
    }
    __syncthreads();
    // wave-0 shuffle scan of the 64 counters (1 barrier instead of 13)
    if (t < 64) {
        int v = cnt[t];
        int sc = v;
        #pragma unroll
        for (int o = 1; o < 64; o <<= 1) {
            int u = __shfl_up(sc, o, 64);
            if (t >= o) sc += u;
        }
        seg[t] = sc;        // inclusive scan
        cur[t] = sc - v;    // exclusive
    }
    __syncthreads();
    for (int i = t; i < m; i += 1024) {
        ull v = stage[i];
        int dl = (int)((uint)(v >> 20) & 63u);
        int p = atomicAdd(&cur[dl], 1);
        sorted[p] = v;
    }
    __syncthreads();
    int wave = t >> 6, lane = t & 63;
    int dl = wave * 4 + (lane >> 4);
    int g = lane & 15;
    int d = b * 64 + dl;
    int c = cnt[dl];
    int s0 = seg[dl] - c;
    float inv = 1.0f / scal[1];
    float acc[8];
    #pragma unroll
    for (int k = 0; k < 8; ++k) acc[k] = 0.0f;
    int j = 0;
    for (; j + 3 < c; j += 4) {
        ull v0 = sorted[s0 + j];
        ull v1 = sorted[s0 + j + 1];
        ull v2 = sorted[s0 + j + 2];
        ull v3 = sorted[s0 + j + 3];
        uint q0 = hs4[(size_t)(uint)(v0 & 0xfffffu) * 16 + g];
        uint q1 = hs4[(size_t)(uint)(v1 & 0xfffffu) * 16 + g];
        uint q2 = hs4[(size_t)(uint)(v2 & 0xfffffu) * 16 + g];
        uint q3 = hs4[(size_t)(uint)(v3 & 0xfffffu) * 16 + g];
        dec8_fma(q0, __uint_as_float((uint)(v0 >> 32)), acc);
        dec8_fma(q1, __uint_as_float((uint)(v1 >> 32)), acc);
        dec8_fma(q2, __uint_as_float((uint)(v2 >> 32)), acc);
        dec8_fma(q3, __uint_as_float((uint)(v3 >> 32)), acc);
    }
    for (; j < c; ++j) {
        ull v = sorted[s0 + j];
        uint q = hs4[(size_t)(uint)(v & 0xfffffu) * 16 + g];
        float w = __uint_as_float((uint)(v >> 32));
        dec8_fma(q, w, acc);
    }
    if (d < N) {
        const float4* b4 = (const float4*)(bias + g * 8);
        float* o = out + (size_t)d * F + g * 8;
        #pragma unroll
        for (int k = 0; k < 2; ++k) {
            float4 bs = b4[k];
            f32x4 r;
            r.x = bs.x + inv * acc[4 * k + 0];
            r.y = bs.y + inv * acc[4 * k + 1];
            r.z = bs.z + inv * acc[4 * k + 2];
            r.w = bs.w + inv * acc[4 * k + 3];
            __builtin_nontemporal_store(r, (f32x4*)(o + 4 * k));
        }
    }
}

// ---------- launch ----------
extern "C" void kernel_launch(void* const* d_in, const int* in_sizes, int n_in,
                              void* d_out, int out_size, void* d_ws, size_t ws_size,
                              hipStream_t stream) {
    const float* h    = (const float*)d_in[0];
    const float* ef   = (const float*)d_in[1];
    const int*   src  = (const int*)d_in[2];
    const int*   dst  = (const int*)d_in[3];
    const float* W    = (const float*)d_in[4];
    const float* bias = (const float*)d_in[5];
    float*       out  = (float*)d_out;

    int N = in_sizes[0] / F;        // 50000
    int E = in_sizes[1];            // 1.6M
    int NBK = (N + 63) >> 6;        // 782 buckets of 64 dsts
    int GB  = (N + 255) >> 8;       // 196 gemm-role blocks (256 rows each)

    // workspace layout
    char*  base = (char*)d_ws;
    float* scal  = (float*)base;                     base += 16 * sizeof(float);
    unsigned short* WT = (unsigned short*)base;      base += F * F * sizeof(unsigned short);
    ull*   ebin  = (ull*)base;                       base += (size_t)NBK * CAP * sizeof(ull);
    unsigned short* hs4 = (unsigned short*)base;     base += (size_t)N * 64;  // fp4: 64 B/row
    int*   bucketCursor = (int*)base;

    size_t fusedLds = (size_t)2 * CAP * 8 + 3 * 64 * 4;

    hipLaunchKernelGGL(k_setup, dim3(64), dim3(256), 0, stream, scal, bucketCursor, W, WT, NBK);
    hipLaunchKernelGGL(k_main,  dim3(GB + SCANB), dim3(1024), 0, stream,
                       h, WT, hs4, N, GB, src, dst, ef, E, NBK, bucketCursor, ebin, scal);
    hipLaunchKernelGGL(k_fused, dim3(NBK), dim3(1024), fusedLds, stream,
                       bucketCursor, ebin, (const uint*)hs4, bias, scal, out, N);
}